// Round 10
// baseline (312.482 us; speedup 1.0000x reference)
//
#include <hip/hip_runtime.h>

#define T_DIM 2048
#define B_DIM 8192
#define PH    256   // phases
#define SPH   8     // steps per phase

// DPP cross-lane helpers (pure VALU)
__device__ __forceinline__ float dpp_qxor1(float v) {
  int i = __float_as_int(v);
  return __int_as_float(__builtin_amdgcn_update_dpp(i, i, 0xB1, 0xF, 0xF, false)); // [1,0,3,2]
}
__device__ __forceinline__ float dpp_qxor2(float v) {
  int i = __float_as_int(v);
  return __int_as_float(__builtin_amdgcn_update_dpp(i, i, 0x4E, 0xF, 0xF, false)); // [2,3,0,1]
}
__device__ __forceinline__ float dpp_qxor3(float v) {
  int i = __float_as_int(v);
  return __int_as_float(__builtin_amdgcn_update_dpp(i, i, 0x1B, 0xF, 0xF, false)); // [3,2,1,0]
}
__device__ __forceinline__ float dpp_hmirror(float v) { // lane l <- lane l^7
  int i = __float_as_int(v);
  return __int_as_float(__builtin_amdgcn_update_dpp(i, i, 0x141, 0xF, 0xF, false));
}

// wid->SIMD is wid%4 (round-robin): wid 0,1 = rec -> SIMD 0,1; wid 2,3 = proj
// -> SIMD 2,3; wid 4,5 = head -> SIMD 0,1. With 2 blocks/CU: SIMD0/1 host
// {2 rec + 2 head}, SIMD2/3 host {2 proj} -> rec density per SIMD doubles.
__global__ __launch_bounds__(384) void lstm_split_kernel(
    const float* __restrict__ x,
    const float* __restrict__ w_ih, const float* __restrict__ w_hh,
    const float* __restrict__ b_ih, const float* __restrict__ b_hh,
    const float* __restrict__ w_lin, const float* __restrict__ b_lin,
    float* __restrict__ out)
{
  __shared__ float2 xaBuf[2][2][64][9];  // [slot][pair][lane][k] {A,B}
  __shared__ float  hnBuf[2][2][64][9];  // [slot][pair][lane][k]

  const int tid  = threadIdx.x;
  const int wid  = tid >> 6;       // 0..5
  const int lane = tid & 63;
  const int pair = wid & 1;

  const float L2E = 1.4426950408889634f;
  const float cm2 = -2.0f * L2E;

  const int l = lane & 7;
  const int half1 = (l >> 2) & 1;            // 0: rows {i,g}; 1: rows {f,o}
  const int e = (l & 3) ^ (half1 ? 3 : 0);   // mirror partner owns same element
  const int grp = lane >> 3;
  const int rA = half1 * 4 + e;              // i | f row
  const int rB = 8 + half1 * 4 + e;          // g | o row
  const float sclA = -L2E;
  const float sclB = half1 ? -L2E : -2.0f * L2E;

  if (wid < 2) {
    // ---------------- recurrence waves (wid 0,1): 257 barriers ----------------
    __builtin_amdgcn_s_setprio(1);
    float whhA[4], whhB[4];
    #pragma unroll
    for (int k = 0; k < 4; ++k) {
      const int j = e ^ k;
      whhA[k] = sclA * w_hh[rA * 4 + j];
      whhB[k] = sclB * w_hh[rB * 4 + j];
    }
    const float sB = half1 ? 1.0f : 2.0f * cm2;  // aB = sB*y + oB
    const float oB = half1 ? 0.0f : -cm2;
    float ct = 0.0f, h0 = 0.0f, h1 = 0.0f, h2 = 0.0f, h3 = 0.0f;

    __syncthreads();  // wait for proj to fill xaBuf[0]

    for (int p = 0; p < PH; ++p) {
      const int d = p & 1;
      float xaA[SPH], xaB[SPH];
      #pragma unroll
      for (int k = 0; k < SPH; ++k) {
        const float2 v = xaBuf[d][pair][lane][k];   // ds_read_b64
        xaA[k] = v.x;
        xaB[k] = v.y;
      }
      #pragma unroll
      for (int k = 0; k < SPH; ++k) {
        float uA = fmaf(whhA[0], h0, xaA[k]);
        uA = fmaf(whhA[1], h1, uA);
        uA = fmaf(whhA[2], h2, uA);
        uA = fmaf(whhA[3], h3, uA);
        float uB = fmaf(whhB[0], h0, xaB[k]);
        uB = fmaf(whhB[1], h1, uB);
        uB = fmaf(whhB[2], h2, uB);
        uB = fmaf(whhB[3], h3, uB);
        const float aA = __builtin_amdgcn_rcpf(1.0f + __builtin_amdgcn_exp2f(uA));
        const float yB = __builtin_amdgcn_rcpf(1.0f + __builtin_amdgcn_exp2f(uB));
        const float aB = fmaf(sB, yB, oB);
        // exchange: half0 sends cm2*(i*tanh g), half1 sends f
        const float Z = half1 ? aA : aA * aB;
        const float W = dpp_hmirror(Z);
        const float F = half1 ? Z : W;
        const float P = half1 ? W : Z;
        ct = fmaf(F, ct, P);                       // ct is cm2-scaled c
        const float zc = __builtin_amdgcn_exp2f(ct);
        const float rc = __builtin_amdgcn_rcpf(1.0f + zc);
        const float Ox = dpp_hmirror(aB);          // ship o to half0
        const float ov = half1 ? aB : Ox;
        const float tc = fmaf(2.0f, rc, -1.0f);    // tanh(c)
        const float hn = ov * tc;
        h0 = hn;
        h1 = dpp_qxor1(hn);
        h2 = dpp_qxor2(hn);
        h3 = dpp_qxor3(hn);
        hnBuf[d][pair][lane][k] = hn;
      }
      __syncthreads();
    }
  } else if (wid < 4) {
    // ---------------- proj/load waves (wid 2,3): 257 barriers ----------------
    const int b = blockIdx.x * 16 + pair * 8 + grp;
    float wihA[4], wihB[4];
    #pragma unroll
    for (int k = 0; k < 4; ++k) {
      const int j = e ^ k;
      wihA[k] = sclA * w_ih[rA * 4 + j];
      wihB[k] = sclB * w_ih[rB * 4 + j];
    }
    const float biasA = sclA * (b_ih[rA] + b_hh[rA]);
    const float biasB = sclB * (b_ih[rB] + b_hh[rB]);

    const int XS = B_DIM * 4;
    const int xoff = b * 4 + e;

    float xc[SPH], xn[SPH];

    auto load8 = [&](float (&dst)[SPH], int ph) {
      const int base = xoff + ((ph & (PH - 1)) * SPH) * XS;  // wrap: harmless
      #pragma unroll
      for (int k = 0; k < SPH; ++k) dst[k] = x[base + k * XS];
    };
    auto projWrite = [&](const float (&xr)[SPH], int dd) {
      #pragma unroll
      for (int k = 0; k < SPH; ++k) {
        const float xe = xr[k];
        const float x1 = dpp_qxor1(xe);
        const float x2 = dpp_qxor2(xe);
        const float x3 = dpp_qxor3(xe);
        float a = fmaf(wihA[0], xe, biasA);
        a = fmaf(wihA[1], x1, a);
        a = fmaf(wihA[2], x2, a);
        a = fmaf(wihA[3], x3, a);
        float bb = fmaf(wihB[0], xe, biasB);
        bb = fmaf(wihB[1], x1, bb);
        bb = fmaf(wihB[2], x2, bb);
        bb = fmaf(wihB[3], x3, bb);
        xaBuf[dd][pair][lane][k] = make_float2(a, bb);   // ds_write_b64
      }
    };

    // prologue: xa for phase 0 -> buf0; start loading x for phase 1
    load8(xc, 0);
    projWrite(xc, 0);
    load8(xn, 1);
    __syncthreads();

    for (int pp = 0; pp < PH; pp += 2) {
      projWrite(xn, 1);           // xa(pp+1) -> buf1
      load8(xc, pp + 2);
      __syncthreads();
      projWrite(xc, 0);           // xa(pp+2) -> buf0
      load8(xn, pp + 3);
      __syncthreads();
    }
  } else {
    // ---------------- head/store waves (wid 4,5): 257 barriers ----------------
    const int og = lane & 7, oj = lane >> 3;
    const int ob = blockIdx.x * 16 + pair * 8 + og;
    float wl[4];
    #pragma unroll
    for (int j = 0; j < 4; ++j) wl[j] = -L2E * w_lin[j];
    const float blin = -L2E * b_lin[0];

    __syncthreads();  // initial barrier (matches other roles)

    for (int p = 0; p < PH; ++p) {
      __syncthreads();  // barrier ending phase p -> hnBuf[p&1] complete
      const int dh = p & 1;
      const float v0 = hnBuf[dh][pair][og * 8 + 0][oj];
      const float v1 = hnBuf[dh][pair][og * 8 + 1][oj];
      const float v2 = hnBuf[dh][pair][og * 8 + 2][oj];
      const float v3 = hnBuf[dh][pair][og * 8 + 3][oj];
      float m = fmaf(wl[0], v0, blin);
      m = fmaf(wl[1], v1, m);
      m = fmaf(wl[2], v2, m);
      m = fmaf(wl[3], v3, m);
      const float o = __builtin_amdgcn_rcpf(1.0f + __builtin_amdgcn_exp2f(m));
      out[(size_t)(p * SPH + oj) * B_DIM + ob] = o;
    }
  }
}

extern "C" void kernel_launch(void* const* d_in, const int* in_sizes, int n_in,
                              void* d_out, int out_size, void* d_ws, size_t ws_size,
                              hipStream_t stream) {
  const float* x     = (const float*)d_in[0];
  const float* w_ih  = (const float*)d_in[1];
  const float* w_hh  = (const float*)d_in[2];
  const float* b_ih  = (const float*)d_in[3];
  const float* b_hh  = (const float*)d_in[4];
  const float* w_lin = (const float*)d_in[5];
  const float* b_lin = (const float*)d_in[6];
  float* out = (float*)d_out;

  // 512 blocks x 384 threads (2 rec + 2 proj + 2 head waves), 16 batch elems
  // per block -> 2 blocks/CU co-resident (27.6 KB LDS each). wid%4 SIMD
  // round-robin concentrates 2 rec waves on SIMD0/1 and 2 proj on SIMD2/3.
  dim3 block(384);
  dim3 grid(B_DIM / 16);
  hipLaunchKernelGGL(lstm_split_kernel, grid, block, 0, stream,
                     x, w_ih, w_hh, b_ih, b_hh, w_lin, b_lin, out);
}

// Round 11
// 274.103 us; speedup vs baseline: 1.1400x; 1.1400x over previous
//
#include <hip/hip_runtime.h>

#define T_DIM 2048
#define B_DIM 8192
#define PH    256   // phases
#define SPH   8     // steps per phase

// DPP cross-lane helpers (pure VALU)
__device__ __forceinline__ float dpp_qxor1(float v) {
  int i = __float_as_int(v);
  return __int_as_float(__builtin_amdgcn_update_dpp(i, i, 0xB1, 0xF, 0xF, false)); // [1,0,3,2]
}
__device__ __forceinline__ float dpp_qxor2(float v) {
  int i = __float_as_int(v);
  return __int_as_float(__builtin_amdgcn_update_dpp(i, i, 0x4E, 0xF, 0xF, false)); // [2,3,0,1]
}
__device__ __forceinline__ float dpp_qxor3(float v) {
  int i = __float_as_int(v);
  return __int_as_float(__builtin_amdgcn_update_dpp(i, i, 0x1B, 0xF, 0xF, false)); // [3,2,1,0]
}
__device__ __forceinline__ float dpp_hmirror(float v) { // lane l <- lane l^7
  int i = __float_as_int(v);
  return __int_as_float(__builtin_amdgcn_update_dpp(i, i, 0x141, 0xF, 0xF, false));
}

__global__ __launch_bounds__(512) void lstm_fused_kernel(
    const float* __restrict__ x,
    const float* __restrict__ w_ih, const float* __restrict__ w_hh,
    const float* __restrict__ b_ih, const float* __restrict__ b_hh,
    const float* __restrict__ w_lin, const float* __restrict__ b_lin,
    float* __restrict__ out)
{
  __shared__ float2 xaBuf[2][4][64][9];  // [slot][pair][lane][k] {A,B}

  const int tid  = threadIdx.x;
  const int wid  = tid >> 6;       // 0..7
  const int lane = tid & 63;
  const int pair = wid & 3;

  const float L2E = 1.4426950408889634f;
  const float cm2 = -2.0f * L2E;

  const int l = lane & 7;
  const int half1 = (l >> 2) & 1;            // 0: rows {i,g}; 1: rows {f,o}
  const int e = (l & 3) ^ (half1 ? 3 : 0);   // mirror partner owns same element
  const int grp = lane >> 3;
  const int rA = half1 * 4 + e;              // i | f row
  const int rB = 8 + half1 * 4 + e;          // g | o row
  const float sclA = -L2E;
  const float sclB = half1 ? -L2E : -2.0f * L2E;

  if (wid < 4) {
    // ---------------- recurrence waves (wid 0..3): 257 barriers ----------------
    __builtin_amdgcn_s_setprio(1);
    float whhA[4], whhB[4], wl[4];
    #pragma unroll
    for (int k = 0; k < 4; ++k) {
      const int j = e ^ k;
      whhA[k] = sclA * w_hh[rA * 4 + j];
      whhB[k] = sclB * w_hh[rB * 4 + j];
      wl[k]   = -L2E * w_lin[j];
    }
    const float blinS = -L2E * b_lin[0];
    // num1 = half0 ? cm2*(1-EB) : 1  ==  fma(nmA, EB, nmB)  (uniform fma)
    const float nmA = half1 ? 0.0f : -cm2;
    const float nmB = half1 ? 1.0f :  cm2;
    // num2 = half1 ? (1-E2) : 1  ==  fma(q2, E2, 1)  (uniform fma)
    const float q2 = half1 ? -1.0f : 0.0f;

    const int b = blockIdx.x * 32 + pair * 8 + grp;  // batch elem for head store
    float ct = 0.0f, h0 = 0.0f, h1v = 0.0f, h2v = 0.0f, h3v = 0.0f;

    __syncthreads();  // wait for proj to fill xaBuf[0]

    for (int p = 0; p < PH; ++p) {
      const int d = p & 1;
      float xaA[SPH], xaB[SPH];
      #pragma unroll
      for (int k = 0; k < SPH; ++k) {
        const float2 v = xaBuf[d][pair][lane][k];   // ds_read_b64
        xaA[k] = v.x;
        xaB[k] = v.y;
      }
      #pragma unroll
      for (int k = 0; k < SPH; ++k) {
        // gate pre-activations (pre-scaled for exp2)
        float uA = fmaf(whhA[0], h0, xaA[k]);
        uA = fmaf(whhA[1], h1v, uA);
        uA = fmaf(whhA[2], h2v, uA);
        uA = fmaf(whhA[3], h3v, uA);
        float uB = fmaf(whhB[0], h0, xaB[k]);
        uB = fmaf(whhB[1], h1v, uB);
        uB = fmaf(whhB[2], h2v, uB);
        uB = fmaf(whhB[3], h3v, uB);

        // head pre-activation for step t-1 (uses incoming h) — off the chain
        float m = fmaf(wl[0], h0, blinS);
        m = fmaf(wl[1], h1v, m);
        m = fmaf(wl[2], h2v, m);
        m = fmaf(wl[3], h3v, m);

        const float EA = __builtin_amdgcn_exp2f(uA);
        const float EB = __builtin_amdgcn_exp2f(uB);
        const float dA = 1.0f + EA;
        const float dB = 1.0f + EB;
        // fused: half0: Z = cm2 * i * tanh(g) = cm2*(1-EB)/(dA*dB); half1: Z = f = 1/dA
        const float s1   = half1 ? 1.0f : dB;
        const float den1 = dA * s1;
        const float r1   = __builtin_amdgcn_rcpf(den1);
        const float nm1  = fmaf(nmA, EB, nmB);
        const float Z    = nm1 * r1;
        // exchange: half0 sends cm2*(i*tanh g), half1 sends f
        const float W = dpp_hmirror(Z);
        const float F = half1 ? Z : W;
        const float P = half1 ? W : Z;
        ct = fmaf(F, ct, P);                       // ct is cm2-scaled c

        // fused second stage: half1: hn = tanh(c)*sigmoid(o) = (1-E2)/(dB*(1+E2));
        //                     half0: head sigma = 1/(1+exp2(m))
        const float ctc  = fminf(ct, 120.0f);      // overflow guard (tanh saturated)
        const float src  = half1 ? ctc : m;
        const float E2   = __builtin_amdgcn_exp2f(src);
        const float d2   = 1.0f + E2;
        const float s2   = half1 ? dB : 1.0f;
        const float den2 = d2 * s2;
        const float r2   = __builtin_amdgcn_rcpf(den2);
        const float nm2  = fmaf(q2, E2, 1.0f);
        const float w    = nm2 * r2;               // h1: hn ; h0: head(t-1)
        const float hm   = dpp_hmirror(w);
        const float hn   = half1 ? w : hm;

        // store head output for step t-1 (lane 0 of each 8-lane group)
        if (p > 0 || k > 0) {
          if (l == 0) out[(size_t)(p * SPH + k - 1) * B_DIM + b] = w;
        }

        // broadcast new h within quad
        h0  = hn;
        h1v = dpp_qxor1(hn);
        h2v = dpp_qxor2(hn);
        h3v = dpp_qxor3(hn);
      }
      __syncthreads();
    }
    // tail: output for t = 2047 from final h
    float m = fmaf(wl[0], h0, blinS);
    m = fmaf(wl[1], h1v, m);
    m = fmaf(wl[2], h2v, m);
    m = fmaf(wl[3], h3v, m);
    const float Et = __builtin_amdgcn_exp2f(m);
    const float ot = __builtin_amdgcn_rcpf(1.0f + Et);
    if (l == 0) out[(size_t)(T_DIM - 1) * B_DIM + b] = ot;
  } else {
    // ---------------- proj/load waves (wid 4..7): 257 barriers ----------------
    const int b = blockIdx.x * 32 + pair * 8 + grp;
    float wihA[4], wihB[4];
    #pragma unroll
    for (int k = 0; k < 4; ++k) {
      const int j = e ^ k;
      wihA[k] = sclA * w_ih[rA * 4 + j];
      wihB[k] = sclB * w_ih[rB * 4 + j];
    }
    const float biasA = sclA * (b_ih[rA] + b_hh[rA]);
    const float biasB = sclB * (b_ih[rB] + b_hh[rB]);

    const int XS = B_DIM * 4;
    const int xoff = b * 4 + e;

    float xc[SPH], xn[SPH];

    auto load8 = [&](float (&dst)[SPH], int ph) {
      const int base = xoff + ((ph & (PH - 1)) * SPH) * XS;  // wrap: harmless
      #pragma unroll
      for (int k = 0; k < SPH; ++k) dst[k] = x[base + k * XS];
    };
    auto projWrite = [&](const float (&xr)[SPH], int dd) {
      #pragma unroll
      for (int k = 0; k < SPH; ++k) {
        const float xe = xr[k];
        const float x1 = dpp_qxor1(xe);
        const float x2 = dpp_qxor2(xe);
        const float x3 = dpp_qxor3(xe);
        float a = fmaf(wihA[0], xe, biasA);
        a = fmaf(wihA[1], x1, a);
        a = fmaf(wihA[2], x2, a);
        a = fmaf(wihA[3], x3, a);
        float bb = fmaf(wihB[0], xe, biasB);
        bb = fmaf(wihB[1], x1, bb);
        bb = fmaf(wihB[2], x2, bb);
        bb = fmaf(wihB[3], x3, bb);
        xaBuf[dd][pair][lane][k] = make_float2(a, bb);   // ds_write_b64
      }
    };

    // prologue: xa for phase 0 -> buf0; start loading x for phase 1
    load8(xc, 0);
    projWrite(xc, 0);
    load8(xn, 1);
    __syncthreads();

    for (int pp = 0; pp < PH; pp += 2) {
      projWrite(xn, 1);           // xa(pp+1) -> buf1
      load8(xc, pp + 2);
      __syncthreads();
      projWrite(xc, 0);           // xa(pp+2) -> buf0
      load8(xn, pp + 3);
      __syncthreads();
    }
  }
}

extern "C" void kernel_launch(void* const* d_in, const int* in_sizes, int n_in,
                              void* d_out, int out_size, void* d_ws, size_t ws_size,
                              hipStream_t stream) {
  const float* x     = (const float*)d_in[0];
  const float* w_ih  = (const float*)d_in[1];
  const float* w_hh  = (const float*)d_in[2];
  const float* b_ih  = (const float*)d_in[3];
  const float* b_hh  = (const float*)d_in[4];
  const float* w_lin = (const float*)d_in[5];
  const float* b_lin = (const float*)d_in[6];
  float* out = (float*)d_out;

  // 256 blocks x 512 threads (4 rec + 4 proj waves), 32 batch elems/block
  // -> 1 block/CU, 2 waves/SIMD {1 rec + 1 proj}. Head role fused into the
  // rec wave's spare half0 trans slots; hnBuf eliminated.
  dim3 block(512);
  dim3 grid(B_DIM / 32);
  hipLaunchKernelGGL(lstm_fused_kernel, grid, block, 0, stream,
                     x, w_ih, w_hh, b_ih, b_hh, w_lin, b_lin, out);
}

// Round 13
// 238.635 us; speedup vs baseline: 1.3095x; 1.1486x over previous
//
#include <hip/hip_runtime.h>

#define T_DIM 2048
#define B_DIM 8192
#define PH    256   // phases
#define SPH   8     // steps per phase

using f32x2 = __attribute__((ext_vector_type(2))) float;

// DPP cross-lane helpers (pure VALU)
__device__ __forceinline__ float dpp_qxor1(float v) {
  int i = __float_as_int(v);
  return __int_as_float(__builtin_amdgcn_update_dpp(i, i, 0xB1, 0xF, 0xF, false)); // [1,0,3,2]
}
__device__ __forceinline__ float dpp_qxor2(float v) {
  int i = __float_as_int(v);
  return __int_as_float(__builtin_amdgcn_update_dpp(i, i, 0x4E, 0xF, 0xF, false)); // [2,3,0,1]
}
__device__ __forceinline__ float dpp_qxor3(float v) {
  int i = __float_as_int(v);
  return __int_as_float(__builtin_amdgcn_update_dpp(i, i, 0x1B, 0xF, 0xF, false)); // [3,2,1,0]
}
__device__ __forceinline__ float dpp_hmirror(float v) { // lane l <- lane l^7
  int i = __float_as_int(v);
  return __int_as_float(__builtin_amdgcn_update_dpp(i, i, 0x141, 0xF, 0xF, false));
}

__global__ __launch_bounds__(768) void lstm_sr_kernel(
    const float* __restrict__ x,
    const float* __restrict__ w_ih, const float* __restrict__ w_hh,
    const float* __restrict__ b_ih, const float* __restrict__ b_hh,
    const float* __restrict__ w_lin, const float* __restrict__ b_lin,
    float* __restrict__ out)
{
  // xa: [slot][pair][k][lane] -> lane-contiguous ds ops
  __shared__ f32x2 xaBuf[2][4][SPH][64];
  // hn: [slot][pair][lane][9] (odd stride)
  __shared__ float hnBuf[2][4][64][9];

  const int tid  = threadIdx.x;
  const int wid  = tid >> 6;       // 0..11
  const int lane = tid & 63;
  const int pair = wid & 3;

  const float L2E = 1.4426950408889634f;
  const float cm2 = -2.0f * L2E;

  const int l = lane & 7;
  const int half1 = (l >> 2) & 1;            // 0: rows {i,g}; 1: rows {f,o}
  const int e = (l & 3) ^ (half1 ? 3 : 0);   // mirror partner owns same element
  const int grp = lane >> 3;
  const int rA = half1 * 4 + e;              // i | f row
  const int rB = 8 + half1 * 4 + e;          // g | o row
  const float sclA = -L2E;
  const float sclB = half1 ? -L2E : -2.0f * L2E;

  if (wid < 4) {
    // ---------------- recurrence waves (wid 0..3): 257 barriers ----------------
    __builtin_amdgcn_s_setprio(1);
    float whhA[4], whhB[4];
    #pragma unroll
    for (int k = 0; k < 4; ++k) {
      const int j = e ^ k;
      whhA[k] = sclA * w_hh[rA * 4 + j];
      whhB[k] = sclB * w_hh[rB * 4 + j];
    }
    const float sB = half1 ? 1.0f : 2.0f * cm2;  // aB = sB*y + oB
    const float oB = half1 ? 0.0f : -cm2;
    float ct = 0.0f, h0 = 0.0f, h1v = 0.0f, h2v = 0.0f, h3v = 0.0f;

    __syncthreads();  // wait for proj to fill xaBuf[0]

    for (int p = 0; p < PH; ++p) {
      const int d = p & 1;
      f32x2 xa2[SPH];
      #pragma unroll
      for (int k = 0; k < SPH; ++k) xa2[k] = xaBuf[d][pair][k][lane];  // ds_read_b64

      #pragma unroll
      for (int k = 0; k < SPH; ++k) {
        // balanced-tree gate accumulation (depth 3)
        float uA = fmaf(whhA[1], h1v, fmaf(whhA[0], h0, xa2[k][0]));
        const float vA = fmaf(whhA[3], h3v, whhA[2] * h2v);
        uA += vA;
        float uB = fmaf(whhB[1], h1v, fmaf(whhB[0], h0, xa2[k][1]));
        const float vB = fmaf(whhB[3], h3v, whhB[2] * h2v);
        uB += vB;

        // shared-rcp double sigmoid: aA = 1/dA, yB = 1/dB via one rcp
        const float EA = __builtin_amdgcn_exp2f(uA);
        const float EB = __builtin_amdgcn_exp2f(uB);
        const float dA = 1.0f + EA;
        const float dB = 1.0f + EB;
        const float r  = __builtin_amdgcn_rcpf(dA * dB);
        const float aA = r * dB;
        const float yB = r * dA;
        const float aB = fmaf(sB, yB, oB);

        // exchange: half0 sends cm2*(i*tanh g), half1 sends f
        const float Z = half1 ? aA : aA * aB;
        const float W = dpp_hmirror(Z);
        const float F = half1 ? Z : W;
        const float P = half1 ? W : Z;
        ct = fmaf(F, ct, P);                       // ct is cm2-scaled c

        const float zc = __builtin_amdgcn_exp2f(ct);
        const float rc = __builtin_amdgcn_rcpf(1.0f + zc);
        const float Ox = dpp_hmirror(aB);          // ship o to half0
        const float ov = half1 ? aB : Ox;
        const float tc = fmaf(2.0f, rc, -1.0f);    // tanh(c)
        const float hn = ov * tc;
        h0  = hn;
        h1v = dpp_qxor1(hn);
        h2v = dpp_qxor2(hn);
        h3v = dpp_qxor3(hn);
        hnBuf[d][pair][lane][k] = hn;
      }
      __syncthreads();
    }
  } else if (wid < 8) {
    // ---------------- proj/load waves (wid 4..7): 257 barriers ----------------
    const int b = blockIdx.x * 32 + pair * 8 + grp;
    float wihA[4], wihB[4];
    #pragma unroll
    for (int k = 0; k < 4; ++k) {
      const int j = e ^ k;
      wihA[k] = sclA * w_ih[rA * 4 + j];
      wihB[k] = sclB * w_ih[rB * 4 + j];
    }
    const float biasA = sclA * (b_ih[rA] + b_hh[rA]);
    const float biasB = sclB * (b_ih[rB] + b_hh[rB]);

    const int XS = B_DIM * 4;
    const int xoff = b * 4 + e;

    float xc[SPH], xn[SPH];

    auto load8 = [&](float (&dst)[SPH], int ph) {
      const int base = xoff + ((ph & (PH - 1)) * SPH) * XS;  // wrap: harmless
      #pragma unroll
      for (int k = 0; k < SPH; ++k) dst[k] = x[base + k * XS];
    };
    auto projWrite = [&](const float (&xr)[SPH], int dd) {
      #pragma unroll
      for (int k = 0; k < SPH; ++k) {
        const float xe = xr[k];
        const float x1 = dpp_qxor1(xe);
        const float x2 = dpp_qxor2(xe);
        const float x3 = dpp_qxor3(xe);
        f32x2 acc;
        float a = fmaf(wihA[0], xe, biasA);
        a = fmaf(wihA[1], x1, a);
        a = fmaf(wihA[2], x2, a);
        a = fmaf(wihA[3], x3, a);
        float bb = fmaf(wihB[0], xe, biasB);
        bb = fmaf(wihB[1], x1, bb);
        bb = fmaf(wihB[2], x2, bb);
        bb = fmaf(wihB[3], x3, bb);
        acc[0] = a;
        acc[1] = bb;
        xaBuf[dd][pair][k][lane] = acc;            // ds_write_b64
      }
    };

    // prologue: xa for phase 0 -> buf0; start loading x for phase 1
    load8(xc, 0);
    projWrite(xc, 0);
    load8(xn, 1);
    __syncthreads();

    for (int pp = 0; pp < PH; pp += 2) {
      projWrite(xn, 1);           // xa(pp+1) -> buf1
      load8(xc, pp + 2);
      __syncthreads();
      projWrite(xc, 0);           // xa(pp+2) -> buf0
      load8(xn, pp + 3);
      __syncthreads();
    }
  } else {
    // ---------------- head/store waves (wid 8..11): 257 barriers ----------------
    const int og = lane & 7, oj = lane >> 3;
    const int ob = blockIdx.x * 32 + pair * 8 + og;
    float wl[4];
    #pragma unroll
    for (int j = 0; j < 4; ++j) wl[j] = -L2E * w_lin[j];
    const float blin = -L2E * b_lin[0];

    __syncthreads();  // initial barrier (matches other roles)

    for (int p = 0; p < PH; ++p) {
      __syncthreads();  // barrier ending phase p -> hnBuf[p&1] complete
      const int dh = p & 1;
      const float v0 = hnBuf[dh][pair][og * 8 + 0][oj];
      const float v1 = hnBuf[dh][pair][og * 8 + 1][oj];
      const float v2 = hnBuf[dh][pair][og * 8 + 2][oj];
      const float v3 = hnBuf[dh][pair][og * 8 + 3][oj];
      float m = fmaf(wl[0], v0, blin);
      m = fmaf(wl[1], v1, m);
      m = fmaf(wl[2], v2, m);
      m = fmaf(wl[3], v3, m);
      const float o = __builtin_amdgcn_rcpf(1.0f + __builtin_amdgcn_exp2f(m));
      out[(size_t)(p * SPH + oj) * B_DIM + ob] = o;
    }
  }
}

extern "C" void kernel_launch(void* const* d_in, const int* in_sizes, int n_in,
                              void* d_out, int out_size, void* d_ws, size_t ws_size,
                              hipStream_t stream) {
  const float* x     = (const float*)d_in[0];
  const float* w_ih  = (const float*)d_in[1];
  const float* w_hh  = (const float*)d_in[2];
  const float* b_ih  = (const float*)d_in[3];
  const float* b_hh  = (const float*)d_in[4];
  const float* w_lin = (const float*)d_in[5];
  const float* b_lin = (const float*)d_in[6];
  float* out = (float*)d_out;

  // R7 champion structure: 256 blocks x 768 threads (4 rec + 4 proj + 4 head),
  // 32 batch elems/block, 1 block/CU, 3 waves/SIMD (one of each role).
  // + shared-rcp sigmoids (6->5 trans/step), balanced-tree u, k-major xa.
  dim3 block(768);
  dim3 grid(B_DIM / 32);
  hipLaunchKernelGGL(lstm_sr_kernel, grid, block, 0, stream,
                     x, w_ih, w_hh, b_ih, b_hh, w_lin, b_lin, out);
}